// Round 1
// baseline (538.935 us; speedup 1.0000x reference)
//
#include <hip/hip_runtime.h>
#include <hip/hip_bf16.h>

#define NPX 16384   // H*W
using bf16 = __hip_bfloat16;

static __device__ __forceinline__ float lrelu(float v) { return v >= 0.f ? v : 0.01f * v; }

// ---------------------------------------------------------------------------
// K1a: feat[b,j,n] = relu(sem[class(j)]) * (x[b,:,n] . Wab[:,j]) + bias_ab[j]
// ---------------------------------------------------------------------------
__global__ __launch_bounds__(256) void k_feat(const float* __restrict__ x,
                                              const float* __restrict__ sem,
                                              const float* __restrict__ wa,
                                              const float* __restrict__ ba,
                                              const float* __restrict__ wb,
                                              const float* __restrict__ bbv,
                                              float* __restrict__ feat)
{
    __shared__ __align__(16) float s_w[64 * 64];   // [c][j]
    __shared__ float s_bias[64];
    int tid = threadIdx.x;
    for (int i = tid; i < 64 * 64; i += 256) {
        int c = i >> 6, j = i & 63;
        float w;
        if (j < 4) w = wa[c * 4 + j];
        else {
            int k = (j - 4) / 3, d = (j - 4) % 3;
            w = wb[k * 192 + c * 3 + d];
        }
        s_w[c * 64 + j] = w;
    }
    if (tid < 64) s_bias[tid] = (tid < 4) ? ba[tid] : bbv[tid - 4];
    __syncthreads();

    int gid = blockIdx.x * 256 + tid;
    int b = gid >> 14, n = gid & (NPX - 1);
    const float* xp = x + (size_t)b * 64 * NPX + n;

    float acc[64];
#pragma unroll
    for (int j = 0; j < 64; ++j) acc[j] = 0.f;
    for (int c = 0; c < 64; ++c) {
        float xc = xp[c * NPX];
        const float4* w4 = reinterpret_cast<const float4*>(s_w + c * 64);
#pragma unroll
        for (int j4 = 0; j4 < 16; ++j4) {
            float4 w = w4[j4];
            acc[j4 * 4 + 0] += xc * w.x; acc[j4 * 4 + 1] += xc * w.y;
            acc[j4 * 4 + 2] += xc * w.z; acc[j4 * 4 + 3] += xc * w.w;
        }
    }
    float sm[21];
    const float* sp = sem + (size_t)b * 21 * NPX + n;
#pragma unroll
    for (int kk = 0; kk < 21; ++kk) sm[kk] = fmaxf(sp[kk * NPX], 0.f);
    float* fp = feat + (size_t)b * 64 * NPX + n;
#pragma unroll
    for (int j = 0; j < 64; ++j) {
        int cls = (j < 4) ? 0 : 1 + (j - 4) / 3;
        fp[j * NPX] = sm[cls] * acc[j] + s_bias[j];
    }
}

// ---------------------------------------------------------------------------
// Generic streamed 64->64 per-pixel matmul: out[b,e,n] = in[b,:,n] . w[:,e] + bias[e]
// ---------------------------------------------------------------------------
__global__ __launch_bounds__(256) void k_gemm64(const float* __restrict__ in,
                                                const float* __restrict__ w,
                                                const float* __restrict__ bias,
                                                float* __restrict__ out)
{
    __shared__ __align__(16) float s_w[64 * 64];
    __shared__ float s_b[64];
    int tid = threadIdx.x;
    for (int i = tid; i < 4096; i += 256) s_w[i] = w[i];
    if (tid < 64) s_b[tid] = bias[tid];
    __syncthreads();

    int gid = blockIdx.x * 256 + tid;
    int b = gid >> 14, n = gid & (NPX - 1);
    const float* ip = in + (size_t)b * 64 * NPX + n;

    float acc[64];
#pragma unroll
    for (int e = 0; e < 64; ++e) acc[e] = 0.f;
    for (int c = 0; c < 64; ++c) {
        float xc = ip[c * NPX];
        const float4* w4 = reinterpret_cast<const float4*>(s_w + c * 64);
#pragma unroll
        for (int e4 = 0; e4 < 16; ++e4) {
            float4 wv = w4[e4];
            acc[e4 * 4 + 0] += xc * wv.x; acc[e4 * 4 + 1] += xc * wv.y;
            acc[e4 * 4 + 2] += xc * wv.z; acc[e4 * 4 + 3] += xc * wv.w;
        }
    }
    float* op = out + (size_t)b * 64 * NPX + n;
#pragma unroll
    for (int e = 0; e < 64; ++e) op[e * NPX] = acc[e] + s_b[e];
}

// Two outputs from one streamed input (k and v from y)
__global__ __launch_bounds__(256) void k_gemm64_dual(const float* __restrict__ in,
                                                     const float* __restrict__ wA,
                                                     const float* __restrict__ bA,
                                                     const float* __restrict__ wB,
                                                     const float* __restrict__ bB,
                                                     float* __restrict__ outA,
                                                     float* __restrict__ outB)
{
    __shared__ __align__(16) float s_wA[64 * 64];
    __shared__ __align__(16) float s_wB[64 * 64];
    __shared__ float s_bA[64], s_bB[64];
    int tid = threadIdx.x;
    for (int i = tid; i < 4096; i += 256) { s_wA[i] = wA[i]; s_wB[i] = wB[i]; }
    if (tid < 64) { s_bA[tid] = bA[tid]; s_bB[tid] = bB[tid]; }
    __syncthreads();

    int gid = blockIdx.x * 256 + tid;
    int b = gid >> 14, n = gid & (NPX - 1);
    const float* ip = in + (size_t)b * 64 * NPX + n;

    float accA[64], accB[64];
#pragma unroll
    for (int e = 0; e < 64; ++e) { accA[e] = 0.f; accB[e] = 0.f; }
    for (int c = 0; c < 64; ++c) {
        float xc = ip[c * NPX];
        const float4* a4 = reinterpret_cast<const float4*>(s_wA + c * 64);
        const float4* b4 = reinterpret_cast<const float4*>(s_wB + c * 64);
#pragma unroll
        for (int e4 = 0; e4 < 16; ++e4) {
            float4 av = a4[e4];
            accA[e4 * 4 + 0] += xc * av.x; accA[e4 * 4 + 1] += xc * av.y;
            accA[e4 * 4 + 2] += xc * av.z; accA[e4 * 4 + 3] += xc * av.w;
            float4 bv = b4[e4];
            accB[e4 * 4 + 0] += xc * bv.x; accB[e4 * 4 + 1] += xc * bv.y;
            accB[e4 * 4 + 2] += xc * bv.z; accB[e4 * 4 + 3] += xc * bv.w;
        }
    }
    float* oA = outA + (size_t)b * 64 * NPX + n;
    float* oB = outB + (size_t)b * 64 * NPX + n;
#pragma unroll
    for (int e = 0; e < 64; ++e) { oA[e * NPX] = accA[e] + s_bA[e]; oB[e * NPX] = accB[e] + s_bB[e]; }
}

// ---------------------------------------------------------------------------
// K2a: h1n = lrelu(LN(x @ w1 + b1))  (64 -> 128), stored bf16
// ---------------------------------------------------------------------------
__global__ __launch_bounds__(256) void k_mlp1(const float* __restrict__ x,
                                              const float* __restrict__ w1,
                                              const float* __restrict__ b1,
                                              const float* __restrict__ g1,
                                              const float* __restrict__ be1,
                                              bf16* __restrict__ h1n)
{
    __shared__ __align__(16) float s_w[64 * 128];
    __shared__ float s_b[128], s_g[128], s_be[128];
    int tid = threadIdx.x;
    for (int i = tid; i < 8192; i += 256) s_w[i] = w1[i];
    for (int i = tid; i < 128; i += 256) { s_b[i] = b1[i]; s_g[i] = g1[i]; s_be[i] = be1[i]; }
    __syncthreads();

    int gid = blockIdx.x * 256 + tid;
    int b = gid >> 14, n = gid & (NPX - 1);
    const float* xp = x + (size_t)b * 64 * NPX + n;

    float acc[128];
#pragma unroll
    for (int d = 0; d < 128; ++d) acc[d] = 0.f;
    for (int c = 0; c < 64; ++c) {
        float xc = xp[c * NPX];
        const float4* w4 = reinterpret_cast<const float4*>(s_w + c * 128);
#pragma unroll
        for (int d4 = 0; d4 < 32; ++d4) {
            float4 wv = w4[d4];
            acc[d4 * 4 + 0] += xc * wv.x; acc[d4 * 4 + 1] += xc * wv.y;
            acc[d4 * 4 + 2] += xc * wv.z; acc[d4 * 4 + 3] += xc * wv.w;
        }
    }
    float mean = 0.f;
#pragma unroll
    for (int d = 0; d < 128; ++d) { acc[d] += s_b[d]; mean += acc[d]; }
    mean *= (1.f / 128.f);
    float var = 0.f;
#pragma unroll
    for (int d = 0; d < 128; ++d) { float t = acc[d] - mean; var += t * t; }
    var *= (1.f / 128.f);
    float rs = rsqrtf(var + 1e-5f);
    bf16* op = h1n + (size_t)b * 128 * NPX + n;
#pragma unroll
    for (int d = 0; d < 128; ++d) {
        float v = (acc[d] - mean) * rs * s_g[d] + s_be[d];
        op[d * NPX] = __float2bfloat16(lrelu(v));
    }
}

// ---------------------------------------------------------------------------
// K2b: h2n = lrelu(LN(h1n @ w2 + b2))  (128 -> 128), two LDS passes
// ---------------------------------------------------------------------------
__global__ __launch_bounds__(256) void k_mlp2(const bf16* __restrict__ h1n,
                                              const float* __restrict__ w2,
                                              const float* __restrict__ b2,
                                              const float* __restrict__ g2,
                                              const float* __restrict__ be2,
                                              bf16* __restrict__ h2n)
{
    __shared__ __align__(16) float s_w[128 * 64];   // half of w2: [cc][dd]
    __shared__ float s_b[128], s_g[128], s_be[128];
    int tid = threadIdx.x;
    for (int i = tid; i < 128; i += 256) { s_b[i] = b2[i]; s_g[i] = g2[i]; s_be[i] = be2[i]; }

    int gid = blockIdx.x * 256 + tid;
    int b = gid >> 14, n = gid & (NPX - 1);
    const bf16* ip = h1n + (size_t)b * 128 * NPX + n;

    float accA[64], accB[64];
#pragma unroll
    for (int d = 0; d < 64; ++d) { accA[d] = 0.f; accB[d] = 0.f; }

    // pass 0: outputs 0..63
    for (int i = tid; i < 8192; i += 256) s_w[i] = w2[(i >> 6) * 128 + (i & 63)];
    __syncthreads();
    for (int cc = 0; cc < 128; ++cc) {
        float hc = __bfloat162float(ip[cc * NPX]);
        const float4* w4 = reinterpret_cast<const float4*>(s_w + cc * 64);
#pragma unroll
        for (int d4 = 0; d4 < 16; ++d4) {
            float4 wv = w4[d4];
            accA[d4 * 4 + 0] += hc * wv.x; accA[d4 * 4 + 1] += hc * wv.y;
            accA[d4 * 4 + 2] += hc * wv.z; accA[d4 * 4 + 3] += hc * wv.w;
        }
    }
    __syncthreads();
    // pass 1: outputs 64..127
    for (int i = tid; i < 8192; i += 256) s_w[i] = w2[(i >> 6) * 128 + 64 + (i & 63)];
    __syncthreads();
    for (int cc = 0; cc < 128; ++cc) {
        float hc = __bfloat162float(ip[cc * NPX]);
        const float4* w4 = reinterpret_cast<const float4*>(s_w + cc * 64);
#pragma unroll
        for (int d4 = 0; d4 < 16; ++d4) {
            float4 wv = w4[d4];
            accB[d4 * 4 + 0] += hc * wv.x; accB[d4 * 4 + 1] += hc * wv.y;
            accB[d4 * 4 + 2] += hc * wv.z; accB[d4 * 4 + 3] += hc * wv.w;
        }
    }

    float mean = 0.f;
#pragma unroll
    for (int d = 0; d < 64; ++d) { accA[d] += s_b[d]; accB[d] += s_b[64 + d]; mean += accA[d] + accB[d]; }
    mean *= (1.f / 128.f);
    float var = 0.f;
#pragma unroll
    for (int d = 0; d < 64; ++d) {
        float t0 = accA[d] - mean, t1 = accB[d] - mean;
        var += t0 * t0 + t1 * t1;
    }
    var *= (1.f / 128.f);
    float rs = rsqrtf(var + 1e-5f);
    bf16* op = h2n + (size_t)b * 128 * NPX + n;
#pragma unroll
    for (int d = 0; d < 64; ++d) {
        float v0 = (accA[d] - mean) * rs * s_g[d] + s_be[d];
        float v1 = (accB[d] - mean) * rs * s_g[64 + d] + s_be[64 + d];
        op[d * NPX] = __float2bfloat16(lrelu(v0));
        op[(64 + d) * NPX] = __float2bfloat16(lrelu(v1));
    }
}

// ---------------------------------------------------------------------------
// K2c: xm = h2n @ w3 + b3  (128 -> 64)
// ---------------------------------------------------------------------------
__global__ __launch_bounds__(256) void k_mlp3(const bf16* __restrict__ h2n,
                                              const float* __restrict__ w3,
                                              const float* __restrict__ b3,
                                              float* __restrict__ xm)
{
    __shared__ __align__(16) float s_w[128 * 64];
    __shared__ float s_b[64];
    int tid = threadIdx.x;
    for (int i = tid; i < 8192; i += 256) s_w[i] = w3[i];
    if (tid < 64) s_b[tid] = b3[tid];
    __syncthreads();

    int gid = blockIdx.x * 256 + tid;
    int b = gid >> 14, n = gid & (NPX - 1);
    const bf16* ip = h2n + (size_t)b * 128 * NPX + n;

    float acc[64];
#pragma unroll
    for (int e = 0; e < 64; ++e) acc[e] = 0.f;
    for (int cc = 0; cc < 128; ++cc) {
        float hc = __bfloat162float(ip[cc * NPX]);
        const float4* w4 = reinterpret_cast<const float4*>(s_w + cc * 64);
#pragma unroll
        for (int e4 = 0; e4 < 16; ++e4) {
            float4 wv = w4[e4];
            acc[e4 * 4 + 0] += hc * wv.x; acc[e4 * 4 + 1] += hc * wv.y;
            acc[e4 * 4 + 2] += hc * wv.z; acc[e4 * 4 + 3] += hc * wv.w;
        }
    }
    float* op = xm + (size_t)b * 64 * NPX + n;
#pragma unroll
    for (int e = 0; e < 64; ++e) op[e * NPX] = acc[e] + s_b[e];
}

// ---------------------------------------------------------------------------
// K4: sum of squares over n for each (q|k, b, c) row
// ---------------------------------------------------------------------------
__global__ __launch_bounds__(256) void k_norm(const float* __restrict__ q,
                                              const float* __restrict__ k,
                                              float* __restrict__ nsq)
{
    __shared__ float s_red[4];
    int bid = blockIdx.x;                        // 0..511
    const float* base = (bid < 256) ? q : k;
    int bc = bid & 255;
    const float* p = base + (size_t)bc * NPX;
    int tid = threadIdx.x;
    float s = 0.f;
    for (int n = tid; n < NPX; n += 256) { float v = p[n]; s += v * v; }
#pragma unroll
    for (int off = 32; off > 0; off >>= 1) s += __shfl_down(s, off);
    if ((tid & 63) == 0) s_red[tid >> 6] = s;
    __syncthreads();
    if (tid == 0) nsq[bid] = s_red[0] + s_red[1] + s_red[2] + s_red[3];
}

// ---------------------------------------------------------------------------
// K5: gram[b,h,d,e] = sum_n q[b,h*16+d,n] * k[b,h*16+e,n]
// ---------------------------------------------------------------------------
__global__ __launch_bounds__(256) void k_gram(const float* __restrict__ q,
                                              const float* __restrict__ k,
                                              float* __restrict__ gram)
{
    __shared__ float s_red[4][16];
    int bid = blockIdx.x;        // ((b*4+h)*16+d)
    int b = bid >> 6;
    int hd = bid & 63;
    int h = hd >> 4;
    const float* qr = q + ((size_t)b * 64 + hd) * NPX;
    const float* kr = k + ((size_t)b * 64 + h * 16) * NPX;
    int tid = threadIdx.x;
    float acc[16];
#pragma unroll
    for (int e = 0; e < 16; ++e) acc[e] = 0.f;
    for (int n = tid; n < NPX; n += 256) {
        float qv = qr[n];
#pragma unroll
        for (int e = 0; e < 16; ++e) acc[e] += qv * kr[e * NPX + n];
    }
    int lane = tid & 63, w = tid >> 6;
#pragma unroll
    for (int e = 0; e < 16; ++e) {
        float v = acc[e];
#pragma unroll
        for (int off = 32; off > 0; off >>= 1) v += __shfl_down(v, off);
        if (lane == 0) s_red[w][e] = v;
    }
    __syncthreads();
    if (tid < 16)
        gram[bid * 16 + tid] = s_red[0][tid] + s_red[1][tid] + s_red[2][tid] + s_red[3][tid];
}

// ---------------------------------------------------------------------------
// K6: attn = softmax_e( rescale[h] * gram / ((|q_d|+eps)(|k_e|+eps)) )
// ---------------------------------------------------------------------------
__global__ __launch_bounds__(256) void k_attn(const float* __restrict__ gram,
                                              const float* __restrict__ nsq,
                                              const float* __restrict__ rescale,
                                              float* __restrict__ attn)
{
    int t = threadIdx.x;            // (b*4+h)*16+d
    int b = t >> 6;
    int hd = t & 63;
    int h = hd >> 4;
    float nq = sqrtf(nsq[b * 64 + hd]) + 1e-8f;
    float rsc = rescale[h];
    float lg[16];
#pragma unroll
    for (int e = 0; e < 16; ++e) {
        float nk = sqrtf(nsq[256 + b * 64 + h * 16 + e]) + 1e-8f;
        lg[e] = rsc * gram[t * 16 + e] / (nq * nk);
    }
    float m = lg[0];
#pragma unroll
    for (int e = 1; e < 16; ++e) m = fmaxf(m, lg[e]);
    float s = 0.f;
#pragma unroll
    for (int e = 0; e < 16; ++e) { lg[e] = expf(lg[e] - m); s += lg[e]; }
    float inv = 1.f / s;
#pragma unroll
    for (int e = 0; e < 16; ++e) attn[t * 16 + e] = lg[e] * inv;
}

// ---------------------------------------------------------------------------
// K7: out[b,cc,n] = sum_he v[b,he,n]*M[he][cc] + bo[cc] + xm[b,cc,n]
//     where M[h*16+e][cc] = sum_d attn[b,h,d,e] * wo[h*16+d][cc]
// ---------------------------------------------------------------------------
__global__ __launch_bounds__(256) void k_out(const float* __restrict__ v,
                                             const float* __restrict__ xm,
                                             const float* __restrict__ attn,
                                             const float* __restrict__ wo,
                                             const float* __restrict__ bo,
                                             float* __restrict__ out)
{
    __shared__ __align__(16) float s_M[64 * 64];
    __shared__ __align__(16) float s_wo[64 * 64];
    __shared__ float s_at[1024];
    __shared__ float s_bo[64];
    int tid = threadIdx.x;
    int b = blockIdx.x >> 6;
    for (int i = tid; i < 4096; i += 256) s_wo[i] = wo[i];
    for (int i = tid; i < 1024; i += 256) s_at[i] = attn[b * 1024 + i];
    if (tid < 64) s_bo[tid] = bo[tid];
    __syncthreads();
    {
        int he = tid >> 2;           // 0..63
        int h = he >> 4, e = he & 15;
        int cc0 = (tid & 3) * 16;
#pragma unroll
        for (int cx = 0; cx < 16; ++cx) {
            int ccv = cc0 + cx;
            float s = 0.f;
#pragma unroll
            for (int d = 0; d < 16; ++d)
                s += s_at[h * 256 + d * 16 + e] * s_wo[(h * 16 + d) * 64 + ccv];
            s_M[he * 64 + ccv] = s;
        }
    }
    __syncthreads();

    int n = (blockIdx.x & 63) * 256 + tid;
    const float* vp = v + (size_t)b * 64 * NPX + n;
    float acc[64];
#pragma unroll
    for (int cc = 0; cc < 64; ++cc) acc[cc] = 0.f;
    for (int he = 0; he < 64; ++he) {
        float vl = vp[he * NPX];
        const float4* m4 = reinterpret_cast<const float4*>(s_M + he * 64);
#pragma unroll
        for (int c4 = 0; c4 < 16; ++c4) {
            float4 mv = m4[c4];
            acc[c4 * 4 + 0] += vl * mv.x; acc[c4 * 4 + 1] += vl * mv.y;
            acc[c4 * 4 + 2] += vl * mv.z; acc[c4 * 4 + 3] += vl * mv.w;
        }
    }
    const float* xp = xm + (size_t)b * 64 * NPX + n;
    float* op = out + (size_t)b * 64 * NPX + n;
#pragma unroll
    for (int cc = 0; cc < 64; ++cc) op[cc * NPX] = acc[cc] + s_bo[cc] + xp[cc * NPX];
}

// ---------------------------------------------------------------------------
extern "C" void kernel_launch(void* const* d_in, const int* in_sizes, int n_in,
                              void* d_out, int out_size, void* d_ws, size_t ws_size,
                              hipStream_t stream)
{
    const float* x    = (const float*)d_in[0];
    const float* sem  = (const float*)d_in[1];
    const float* wa   = (const float*)d_in[2];
    const float* ba   = (const float*)d_in[3];
    const float* wb   = (const float*)d_in[4];
    const float* bbv  = (const float*)d_in[5];
    const float* in_w = (const float*)d_in[6];
    const float* in_b = (const float*)d_in[7];
    const float* w1   = (const float*)d_in[8];
    const float* b1   = (const float*)d_in[9];
    const float* g1   = (const float*)d_in[10];
    const float* be1  = (const float*)d_in[11];
    const float* w2   = (const float*)d_in[12];
    const float* b2   = (const float*)d_in[13];
    const float* g2   = (const float*)d_in[14];
    const float* be2  = (const float*)d_in[15];
    const float* w3   = (const float*)d_in[16];
    const float* b3   = (const float*)d_in[17];
    const float* wq   = (const float*)d_in[18];
    const float* bq   = (const float*)d_in[19];
    const float* wk   = (const float*)d_in[20];
    const float* bk   = (const float*)d_in[21];
    const float* wv   = (const float*)d_in[22];
    const float* bv   = (const float*)d_in[23];
    const float* wo   = (const float*)d_in[24];
    const float* bo   = (const float*)d_in[25];
    const float* rescale = (const float*)d_in[26];

    float* ws = (float*)d_ws;
    const size_t SEG = (size_t)4 * 64 * NPX;   // 4,194,304 floats = 16 MB
    float* feat = ws;                  // [K1a -> K1b], later reused as q
    float* q    = ws;
    float* y    = ws + SEG;            // [K1b -> K3b]
    bf16*  h1n  = (bf16*)(ws + 2 * SEG);   // [K2a -> K2b], later reused as k
    float* kk   = ws + 2 * SEG;
    bf16*  h2n  = (bf16*)(ws + 3 * SEG);   // [K2b -> K2c], later reused as v
    float* vv   = ws + 3 * SEG;
    float* xm   = ws + 4 * SEG;        // [K2c -> K7]
    float* nsq  = ws + 5 * SEG;        // 512 floats
    float* gram = nsq + 512;           // 4096 floats
    float* attn = gram + 4096;         // 4096 floats

    dim3 blk(256), grd(256);
    k_feat<<<grd, blk, 0, stream>>>(x, sem, wa, ba, wb, bbv, feat);
    k_gemm64<<<grd, blk, 0, stream>>>(feat, in_w, in_b, y);
    k_mlp1<<<grd, blk, 0, stream>>>(x, w1, b1, g1, be1, h1n);
    k_mlp2<<<grd, blk, 0, stream>>>(h1n, w2, b2, g2, be2, h2n);
    k_mlp3<<<grd, blk, 0, stream>>>(h2n, w3, b3, xm);
    k_gemm64<<<grd, blk, 0, stream>>>(xm, wq, bq, q);
    k_gemm64_dual<<<grd, blk, 0, stream>>>(y, wk, bk, wv, bv, kk, vv);
    k_norm<<<dim3(512), blk, 0, stream>>>(q, kk, nsq);
    k_gram<<<grd, blk, 0, stream>>>(q, kk, gram);
    k_attn<<<dim3(1), blk, 0, stream>>>(gram, nsq, rescale, attn);
    k_out<<<grd, blk, 0, stream>>>(vv, xm, attn, wo, bo, (float*)d_out);
}